// Round 1
// baseline (242.333 us; speedup 1.0000x reference)
//
#include <hip/hip_runtime.h>

#define NB 64      // L*B batches
#define T 1024     // t1 == t2
#define HD 128     // h

// encoded +inf for order-preserving float-as-uint atomicMin
#define EINF 0xFF800000u

typedef __attribute__((ext_vector_type(8))) short bf16x8;
typedef __attribute__((ext_vector_type(4))) float f32x4;

static __device__ __forceinline__ short f2bf(float f) {
    unsigned u = __float_as_uint(f);
    u += 0x7FFFu + ((u >> 16) & 1u);
    return (short)(u >> 16);
}
static __device__ __forceinline__ unsigned fenc(float f) {
    unsigned b = __float_as_uint(f);
    return b ^ (unsigned)(((int)b >> 31) | (int)0x80000000);
}
static __device__ __forceinline__ float fdec(unsigned u) {
    unsigned m = (~(unsigned)((int)u >> 31)) | 0x80000000u;
    return __uint_as_float(u ^ m);
}

// Phase 0: y fp32 -> bf16 + y row norms + workspace init. ~51 MB, pure BW.
__global__ void wmd_prep(const float* __restrict__ y, short* __restrict__ ybf,
                         float* __restrict__ y2,
                         unsigned* __restrict__ g_colmin, unsigned* __restrict__ g_rowmin,
                         float* __restrict__ sums, unsigned* __restrict__ batch_cnt,
                         unsigned* __restrict__ g_cnt) {
    int gi = blockIdx.x * 256 + threadIdx.x;          // float4 index, 2.097M total
    float4 vy = reinterpret_cast<const float4*>(y)[gi];
    short4 sy;
    sy.x = f2bf(vy.x); sy.y = f2bf(vy.y); sy.z = f2bf(vy.z); sy.w = f2bf(vy.w);
    reinterpret_cast<short4*>(ybf)[gi] = sy;
    float py = vy.x * vy.x + vy.y * vy.y + vy.z * vy.z + vy.w * vy.w;
    py += __shfl_xor(py, 1);  py += __shfl_xor(py, 2);  py += __shfl_xor(py, 4);
    py += __shfl_xor(py, 8);  py += __shfl_xor(py, 16);
    if ((threadIdx.x & 31) == 0) y2[gi >> 5] = py;
    if (gi < NB * T) { g_colmin[gi] = EINF; g_rowmin[gi] = EINF; }
    if (gi < 2) sums[gi] = 0.f;
    if (gi >= 4 && gi < 4 + NB) batch_cnt[gi - 4] = 0u;
    if (gi == 4 + NB) g_cnt[0] = 0u;
}

// Phase 1: fused bf16-MFMA GEMM + min tracking + fence-free per-batch reduce.
// 1024 blocks x 512 threads (8 waves). Block tile: 256 rows x 256 cols
// (batch n x 4 i-tiles x 4 j-quarters). B streamed as 4 tiles of 64x128 bf16
// through a 3-buffer LDS ring with COUNTED vmcnt (never 0 in the loop): tile
// jt+2 is issued at the top of jt, so every DMA has a 2-phase flight window
// instead of the old 1-phase issue->drain-at-__syncthreads lockstep.
// Raw s_barrier + explicit s_waitcnt + sched_barrier(0) replace __syncthreads
// in the loop so the compiler cannot re-insert a vmcnt(0) drain.
// bid%8 picks the XCD slot: all 16 blocks of a batch share one XCD's L2
// (x row-panels reused 4x, ybf quarter-panels reused 4x, both XCD-local).
__global__ __launch_bounds__(512, 4)
void wmd_main(const float* __restrict__ x, const short* __restrict__ ybf,
              const float* __restrict__ y2g,
              unsigned* __restrict__ g_colmin, unsigned* __restrict__ g_rowmin,
              float* __restrict__ sums, unsigned* __restrict__ batch_cnt,
              unsigned* __restrict__ g_cnt, float* __restrict__ out) {
    __shared__ short b_sm[3][64 * 128];        // 3 x 16 KB ring
    __shared__ float y2_sm[256];
    __shared__ float x2_sm[256];
    __shared__ unsigned col_min_sm[256];
    __shared__ unsigned last_sm;
    __shared__ float red_sm[16];

    const int tid  = threadIdx.x;
    const int bid  = blockIdx.x;                       // 0..1023
    const int n    = ((bid & 7) << 3) | ((bid >> 3) & 7);  // batch; xcd = n>>3
    const int tle  = bid >> 6;                         // 0..15
    const int m    = tle >> 2;                         // i-tile (256 rows)
    const int jq   = tle & 3;                          // j-quarter (256 cols)
    const int i0   = m * 256;
    const int j0   = jq * 256;
    const int lane = tid & 63;
    const int wave = tid >> 6;                         // 0..7
    const int l16  = lane & 15, quad = lane >> 4;
    const float FINF = __uint_as_float(0x7F800000u);

    if (tid < 256) col_min_sm[tid] = EINF;

// per wave: 2 x global_load_lds(16B) per tile; linear LDS dest, XOR-swizzled
// global source (both-sides-or-neither rule: reader applies the same XOR).
#define ISSUE_GLLS(pbuf, jtile)                                                   \
    {                                                                             \
        const short* ybase = ybf + (((size_t)(n * T + j0 + (jtile) * 64)) << 7);  \
        _Pragma("unroll")                                                         \
        for (int it = 0; it < 2; ++it) {                                          \
            int g   = wave * 2 + it;                                              \
            int s   = g * 64 + lane;                                              \
            int row = s >> 4;                                                     \
            int c   = (s & 15) ^ (row & 7);                                       \
            const short* gp = ybase + row * 128 + c * 8;                          \
            __builtin_amdgcn_global_load_lds(                                     \
                (const __attribute__((address_space(1))) void*)gp,                \
                (__attribute__((address_space(3))) void*)&b_sm[pbuf][g * 512],    \
                16, 0, 0);                                                        \
        }                                                                         \
    }

    ISSUE_GLLS(0, 0);   // tiles 0 and 1 DMA overlap the prologue
    ISSUE_GLLS(1, 1);

    // ---- A fragments: fp32 x -> bf16 regs + exact fp32 row norms ----
    bf16x8 af[2][4];
    #pragma unroll
    for (int mi = 0; mi < 2; ++mi) {
        float part = 0.f;
        #pragma unroll
        for (int kk = 0; kk < 4; ++kk) {
            const float4* gp = reinterpret_cast<const float4*>(
                x + (((size_t)(n * T + i0 + wave * 32 + mi * 16 + l16)) << 7) + kk * 32 + quad * 8);
            float4 a = gp[0], b = gp[1];
            bf16x8 f;
            f[0] = f2bf(a.x); f[1] = f2bf(a.y); f[2] = f2bf(a.z); f[3] = f2bf(a.w);
            f[4] = f2bf(b.x); f[5] = f2bf(b.y); f[6] = f2bf(b.z); f[7] = f2bf(b.w);
            af[mi][kk] = f;
            part += a.x * a.x + a.y * a.y + a.z * a.z + a.w * a.w;
            part += b.x * b.x + b.y * b.y + b.z * b.z + b.w * b.w;
        }
        part += __shfl_xor(part, 16);
        part += __shfl_xor(part, 32);
        if (quad == 0) x2_sm[wave * 32 + mi * 16 + l16] = part;
    }
    if (tid < 256) y2_sm[tid] = y2g[n * T + j0 + tid];

    float rmin[8];
    #pragma unroll
    for (int q = 0; q < 8; ++q) rmin[q] = FINF;

    // prologue sync: own ds_writes visible; tile-0 DMA is already retired
    // (the x-loads above are younger in the in-order vmcnt queue).
    __builtin_amdgcn_sched_barrier(0);
    asm volatile("s_waitcnt lgkmcnt(0)" ::: "memory");
    __builtin_amdgcn_s_barrier();
    __builtin_amdgcn_sched_barrier(0);

    float x2v[8];
    #pragma unroll
    for (int mi = 0; mi < 2; ++mi)
        #pragma unroll
        for (int r = 0; r < 4; ++r)
            x2v[mi * 4 + r] = x2_sm[wave * 32 + mi * 16 + quad * 4 + r];

    for (int jt = 0; jt < 4; ++jt) {
        const int p = jt % 3;                       // current tile's ring slot
        // issue tile jt+2 into slot (jt+2)%3 == (jt-1)%3: that slot's reads
        // finished at jt-1 and the jt-1 end-barrier has been passed by all waves.
        if (jt < 2) ISSUE_GLLS((jt + 2) % 3, jt + 2);

        float y2v[4];
        #pragma unroll
        for (int ni = 0; ni < 4; ++ni)
            y2v[ni] = y2_sm[jt * 64 + ni * 16 + l16];

        f32x4 acc[2][4];
        #pragma unroll
        for (int mi = 0; mi < 2; ++mi)
            #pragma unroll
            for (int ni = 0; ni < 4; ++ni) {
                f32x4 z = {0.f, 0.f, 0.f, 0.f};
                acc[mi][ni] = z;
            }

        #pragma unroll
        for (int kk = 0; kk < 4; ++kk) {
            bf16x8 bv[4];
            #pragma unroll
            for (int ni = 0; ni < 4; ++ni) {
                int row = ni * 16 + l16;
                int c   = (kk * 4 + quad) ^ (row & 7);
                bv[ni] = *reinterpret_cast<const bf16x8*>(&b_sm[p][(row * 16 + c) * 8]);
            }
            #pragma unroll
            for (int mi = 0; mi < 2; ++mi)
                #pragma unroll
                for (int ni = 0; ni < 4; ++ni)
                    acc[mi][ni] = __builtin_amdgcn_mfma_f32_16x16x32_bf16(
                        af[mi][kk], bv[ni], acc[mi][ni], 0, 0, 0);
        }

        // ---- epilogue: fold mins (norm-add deferred to flush) ----
        float vcol[4] = {FINF, FINF, FINF, FINF};
        #pragma unroll
        for (int mi = 0; mi < 2; ++mi)
            #pragma unroll
            for (int r = 0; r < 4; ++r) {
                float x2r = x2v[mi * 4 + r];
                #pragma unroll
                for (int ni = 0; ni < 4; ++ni) {
                    float xy = acc[mi][ni][r];
                    rmin[mi * 4 + r] = fminf(rmin[mi * 4 + r], fmaf(-2.f, xy, y2v[ni]));
                    vcol[ni]         = fminf(vcol[ni],         fmaf(-2.f, xy, x2r));
                }
            }
        #pragma unroll
        for (int ni = 0; ni < 4; ++ni) {
            float v = vcol[ni];
            v = fminf(v, __shfl_xor(v, 16));
            v = fminf(v, __shfl_xor(v, 32));
            if (lane < 16)
                atomicMin(&col_min_sm[jt * 64 + ni * 16 + lane], fenc(v));
        }

        // ---- counted end-of-phase sync: tile jt+1 must have landed; tile
        // jt+2 (2 own loads) stays in flight across the barrier. ----
        if (jt < 3) {
            __builtin_amdgcn_sched_barrier(0);
            if (jt < 2) asm volatile("s_waitcnt vmcnt(2)" ::: "memory");
            else        asm volatile("s_waitcnt vmcnt(0)" ::: "memory");
            __builtin_amdgcn_s_barrier();
            __builtin_amdgcn_sched_barrier(0);
        }
    }

    // ---- flush mins to global with norms pre-added (device-scope atomics) ----
    __syncthreads();    // vmcnt already 0; drains LDS atomics, orders col_min_sm reads
    if (tid < 256) {
        float v = fdec(col_min_sm[tid]) + y2_sm[tid];       // + y2_j for col tid
        atomicMin(&g_colmin[n * T + j0 + tid], fenc(v));
    }
    #pragma unroll
    for (int mi = 0; mi < 2; ++mi)
        #pragma unroll
        for (int r = 0; r < 4; ++r) {
            float v = rmin[mi * 4 + r] + x2v[mi * 4 + r];   // + x2_i for this row
            v = fminf(v, __shfl_xor(v, 1));
            v = fminf(v, __shfl_xor(v, 2));
            v = fminf(v, __shfl_xor(v, 4));
            v = fminf(v, __shfl_xor(v, 8));
            if (l16 == 0)
                atomicMin(&g_rowmin[n * T + i0 + wave * 32 + mi * 16 + quad * 4 + r], fenc(v));
        }

    // ---- fence-free completion protocol (16 blocks per batch) ----
    __builtin_amdgcn_s_waitcnt(0);   // this wave's atomics acked at coherent point
    __syncthreads();                 // all waves of block done
    if (tid == 0)
        last_sm = __hip_atomic_fetch_add(&batch_cnt[n], 1u, __ATOMIC_RELAXED,
                                         __HIP_MEMORY_SCOPE_AGENT);
    __syncthreads();
    if (last_sm != 15u) return;

    // last block of batch n: reduce its 1024 row/col mins (already full d^2)
    float sc = 0.f, sr = 0.f;
    for (int e = tid; e < T; e += 512) {
        unsigned cu = __hip_atomic_load(&g_colmin[n * T + e], __ATOMIC_RELAXED,
                                        __HIP_MEMORY_SCOPE_AGENT);
        unsigned ru = __hip_atomic_load(&g_rowmin[n * T + e], __ATOMIC_RELAXED,
                                        __HIP_MEMORY_SCOPE_AGENT);
        sc += sqrtf(fmaxf(fdec(cu), 0.f));
        sr += sqrtf(fmaxf(fdec(ru), 0.f));
    }
    #pragma unroll
    for (int o = 1; o < 64; o <<= 1) {
        sc += __shfl_xor(sc, o);
        sr += __shfl_xor(sr, o);
    }
    if (lane == 0) { red_sm[wave] = sc; red_sm[8 + wave] = sr; }
    __syncthreads();
    if (tid == 0) {
        float a = 0.f, b = 0.f;
        #pragma unroll
        for (int w = 0; w < 8; ++w) { a += red_sm[w]; b += red_sm[8 + w]; }
        atomicAdd(&sums[0], a);
        atomicAdd(&sums[1], b);
        __builtin_amdgcn_s_waitcnt(0);   // sums adds acked before counter bump
        unsigned old = __hip_atomic_fetch_add(g_cnt, 1u, __ATOMIC_RELAXED,
                                              __HIP_MEMORY_SCOPE_AGENT);
        if (old == NB - 1) {
            float fa = __hip_atomic_load(&sums[0], __ATOMIC_RELAXED, __HIP_MEMORY_SCOPE_AGENT);
            float fb = __hip_atomic_load(&sums[1], __ATOMIC_RELAXED, __HIP_MEMORY_SCOPE_AGENT);
            out[0] = fmaxf(fa, fb) * (1.0f / 67108864.0f);
        }
    }
}

extern "C" void kernel_launch(void* const* d_in, const int* in_sizes, int n_in,
                              void* d_out, int out_size, void* d_ws, size_t ws_size,
                              hipStream_t stream) {
    const float* x = (const float*)d_in[0];
    const float* y = (const float*)d_in[1];
    float* out = (float*)d_out;

    char* ws = (char*)d_ws;
    unsigned* g_colmin  = (unsigned*)(ws);                     // 256 KB
    unsigned* g_rowmin  = (unsigned*)(ws + 256 * 1024);        // 256 KB
    float*    y2g       = (float*)(ws + 512 * 1024);           // 256 KB
    float*    sums      = (float*)(ws + 768 * 1024);           // 2 f32
    unsigned* batch_cnt = (unsigned*)(ws + 768 * 1024 + 256);  // 64 u32
    unsigned* g_cnt     = (unsigned*)(ws + 768 * 1024 + 2048); // 1 u32
    short*    ybf       = (short*)(ws + 1024 * 1024);          // 16 MB

    wmd_prep<<<(NB * T * HD / 4) / 256, 256, 0, stream>>>(
        y, ybf, y2g, g_colmin, g_rowmin, sums, batch_cnt, g_cnt);
    wmd_main<<<dim3(1024), 512, 0, stream>>>(
        x, ybf, y2g, g_colmin, g_rowmin, sums, batch_cnt, g_cnt, out);
}

// Round 2
// 128.411 us; speedup vs baseline: 1.8872x; 1.8872x over previous
//
#include <hip/hip_runtime.h>

#define NB 64      // L*B batches
#define T 1024     // t1 == t2
#define HD 128     // h

// encoded +inf for order-preserving float-as-uint atomicMin
#define EINF 0xFF800000u

typedef __attribute__((ext_vector_type(8))) short bf16x8;
typedef __attribute__((ext_vector_type(4))) float f32x4;

static __device__ __forceinline__ short f2bf(float f) {
    unsigned u = __float_as_uint(f);
    u += 0x7FFFu + ((u >> 16) & 1u);
    return (short)(u >> 16);
}
static __device__ __forceinline__ unsigned fenc(float f) {
    unsigned b = __float_as_uint(f);
    return b ^ (unsigned)(((int)b >> 31) | (int)0x80000000);
}
static __device__ __forceinline__ float fdec(unsigned u) {
    unsigned m = (~(unsigned)((int)u >> 31)) | 0x80000000u;
    return __uint_as_float(u ^ m);
}

// Phase 0: y fp32 -> bf16 + y row norms + workspace init. ~51 MB, pure BW.
__global__ void wmd_prep(const float* __restrict__ y, short* __restrict__ ybf,
                         float* __restrict__ y2,
                         unsigned* __restrict__ g_colmin, unsigned* __restrict__ g_rowmin,
                         float* __restrict__ sums, unsigned* __restrict__ batch_cnt,
                         unsigned* __restrict__ g_cnt) {
    int gi = blockIdx.x * 256 + threadIdx.x;          // float4 index, 2.097M total
    float4 vy = reinterpret_cast<const float4*>(y)[gi];
    short4 sy;
    sy.x = f2bf(vy.x); sy.y = f2bf(vy.y); sy.z = f2bf(vy.z); sy.w = f2bf(vy.w);
    reinterpret_cast<short4*>(ybf)[gi] = sy;
    float py = vy.x * vy.x + vy.y * vy.y + vy.z * vy.z + vy.w * vy.w;
    py += __shfl_xor(py, 1);  py += __shfl_xor(py, 2);  py += __shfl_xor(py, 4);
    py += __shfl_xor(py, 8);  py += __shfl_xor(py, 16);
    if ((threadIdx.x & 31) == 0) y2[gi >> 5] = py;
    if (gi < NB * T) { g_colmin[gi] = EINF; g_rowmin[gi] = EINF; }
    if (gi < 2) sums[gi] = 0.f;
    if (gi >= 4 && gi < 4 + NB) batch_cnt[gi - 4] = 0u;
    if (gi == 4 + NB) g_cnt[0] = 0u;
}

// Phase 1: fused bf16-MFMA GEMM + min tracking + fence-free per-batch reduce.
// Round-0 structure (1024 blocks x 256 threads, per-block 128 rows x 512 cols,
// same prologue/flush/completion), with ONE change: the B stream is 16 tiles
// of 32 cols (8 KB) through a 4-slot LDS ring (32 KB total — same footprint
// as the old 2x16KB double buffer, so 4 blocks/CU is preserved), synced with
// COUNTED vmcnt. Phase jt issues tile jt+3; the end-of-phase wait is
// s_waitcnt vmcnt(4) (tiles jt+2 and jt+3 stay in flight ACROSS the barrier),
// so each DMA has a ~2.5-phase flight window instead of the old
// issue->drain-at-__syncthreads lockstep. Only the last two phases drain.
// NO sched_barrier(0) anywhere (round-1 post-mortem: suspected spill trigger);
// ordering relies on memory-clobbered asm around the raw s_barrier.
__global__ __launch_bounds__(256, 4)
void wmd_main(const float* __restrict__ x, const short* __restrict__ ybf,
              const float* __restrict__ y2g,
              unsigned* __restrict__ g_colmin, unsigned* __restrict__ g_rowmin,
              float* __restrict__ sums, unsigned* __restrict__ batch_cnt,
              unsigned* __restrict__ g_cnt, float* __restrict__ out) {
    __shared__ short b_sm[4][32 * 128];        // 4 x 8 KB ring
    __shared__ float y2_sm[512];
    __shared__ float x2_sm[128];
    __shared__ unsigned col_min_sm[512];
    __shared__ unsigned last_sm;
    __shared__ float red_sm[8];

    const int tid  = threadIdx.x;
    const int lin  = blockIdx.y * 16 + blockIdx.x;   // 0..1023
    const int m    = (lin >> 3) & 7;                 // i-tile 0..7
    const int grp  = ((lin >> 6) << 3) | (lin & 7);  // 0..127: (n, j-half) group
    const int n    = grp >> 1;
    const int i0   = m * 128;
    const int j0   = (grp & 1) * 512;
    const int lane = tid & 63;
    const int wave = tid >> 6;
    const int l16  = lane & 15, quad = lane >> 4;
    const float FINF = __uint_as_float(0x7F800000u);

    #pragma unroll
    for (int e = tid; e < 512; e += 256) col_min_sm[e] = EINF;

// per wave: 2 x global_load_lds(16B) per 32-col tile; linear LDS dest,
// XOR-swizzled global source (reader applies the same XOR).
#define ISSUE_GLLS(pbuf, jtile)                                                   \
    {                                                                             \
        const short* ybase = ybf + (((size_t)(n * T + j0 + (jtile) * 32)) << 7);  \
        _Pragma("unroll")                                                         \
        for (int it = 0; it < 2; ++it) {                                          \
            int g   = wave * 2 + it;                                              \
            int s   = g * 64 + lane;                                              \
            int row = s >> 4;                                                     \
            int c   = (s & 15) ^ (row & 7);                                       \
            const short* gp = ybase + row * 128 + c * 8;                          \
            __builtin_amdgcn_global_load_lds(                                     \
                (const __attribute__((address_space(1))) void*)gp,                \
                (__attribute__((address_space(3))) void*)&b_sm[pbuf][g * 512],    \
                16, 0, 0);                                                        \
        }                                                                         \
    }

    // tiles 0..2 DMA overlap the prologue (drained by the x-load consumption:
    // vmcnt retires in order, the x loads below are younger).
    ISSUE_GLLS(0, 0);
    ISSUE_GLLS(1, 1);
    ISSUE_GLLS(2, 2);

    // ---- A fragments: fp32 x -> bf16 regs + exact fp32 row norms ----
    bf16x8 af[2][4];
    #pragma unroll
    for (int mi = 0; mi < 2; ++mi) {
        float part = 0.f;
        #pragma unroll
        for (int kk = 0; kk < 4; ++kk) {
            const float4* gp = reinterpret_cast<const float4*>(
                x + (((size_t)(n * T + i0 + wave * 32 + mi * 16 + l16)) << 7) + kk * 32 + quad * 8);
            float4 a = gp[0], b = gp[1];
            bf16x8 f;
            f[0] = f2bf(a.x); f[1] = f2bf(a.y); f[2] = f2bf(a.z); f[3] = f2bf(a.w);
            f[4] = f2bf(b.x); f[5] = f2bf(b.y); f[6] = f2bf(b.z); f[7] = f2bf(b.w);
            af[mi][kk] = f;
            part += a.x * a.x + a.y * a.y + a.z * a.z + a.w * a.w;
            part += b.x * b.x + b.y * b.y + b.z * b.z + b.w * b.w;
        }
        part += __shfl_xor(part, 16);
        part += __shfl_xor(part, 32);
        if (quad == 0) x2_sm[wave * 32 + mi * 16 + l16] = part;
    }
    #pragma unroll
    for (int e = tid; e < 512; e += 256) y2_sm[e] = y2g[n * T + j0 + e];

    float rmin[8];
    #pragma unroll
    for (int q = 0; q < 8; ++q) rmin[q] = FINF;

    __syncthreads();    // x2_sm/y2_sm visible; tiles 0-2 DMA drained by x use

    float x2v[8];
    #pragma unroll
    for (int mi = 0; mi < 2; ++mi)
        #pragma unroll
        for (int r = 0; r < 4; ++r)
            x2v[mi * 4 + r] = x2_sm[wave * 32 + mi * 16 + quad * 4 + r];

    for (int jt = 0; jt < 16; ++jt) {
        const int p = jt & 3;                       // current tile's ring slot
        // issue tile jt+3 into slot (jt+3)&3 == (jt-1)&3: that slot's reads
        // finished in phase jt-1, whose end-barrier every wave has passed.
        if (jt < 13) ISSUE_GLLS((jt + 3) & 3, jt + 3);

        float y2v[2];
        #pragma unroll
        for (int ni = 0; ni < 2; ++ni)
            y2v[ni] = y2_sm[jt * 32 + ni * 16 + l16];

        f32x4 acc[2][2];
        #pragma unroll
        for (int mi = 0; mi < 2; ++mi)
            #pragma unroll
            for (int ni = 0; ni < 2; ++ni) {
                f32x4 z = {0.f, 0.f, 0.f, 0.f};
                acc[mi][ni] = z;
            }

        #pragma unroll
        for (int kk = 0; kk < 4; ++kk) {
            bf16x8 bv[2];
            #pragma unroll
            for (int ni = 0; ni < 2; ++ni) {
                int row = ni * 16 + l16;
                int c   = (kk * 4 + quad) ^ (row & 7);
                bv[ni] = *reinterpret_cast<const bf16x8*>(&b_sm[p][(row * 16 + c) * 8]);
            }
            #pragma unroll
            for (int mi = 0; mi < 2; ++mi)
                #pragma unroll
                for (int ni = 0; ni < 2; ++ni)
                    acc[mi][ni] = __builtin_amdgcn_mfma_f32_16x16x32_bf16(
                        af[mi][kk], bv[ni], acc[mi][ni], 0, 0, 0);
        }

        // ---- epilogue: fold mins (norm-add deferred to flush) ----
        float vcol[2] = {FINF, FINF};
        #pragma unroll
        for (int mi = 0; mi < 2; ++mi)
            #pragma unroll
            for (int r = 0; r < 4; ++r) {
                float x2r = x2v[mi * 4 + r];
                #pragma unroll
                for (int ni = 0; ni < 2; ++ni) {
                    float xy = acc[mi][ni][r];
                    rmin[mi * 4 + r] = fminf(rmin[mi * 4 + r], fmaf(-2.f, xy, y2v[ni]));
                    vcol[ni]         = fminf(vcol[ni],         fmaf(-2.f, xy, x2r));
                }
            }
        #pragma unroll
        for (int ni = 0; ni < 2; ++ni) {
            float v = vcol[ni];
            v = fminf(v, __shfl_xor(v, 16));
            v = fminf(v, __shfl_xor(v, 32));
            if (lane < 16)
                atomicMin(&col_min_sm[jt * 32 + ni * 16 + lane], fenc(v));
        }

        // ---- counted end-of-phase sync: tile jt+1 must have landed (this
        // wave's 2 loads for it are the oldest outstanding); tiles jt+2/jt+3
        // (4 loads) stay in flight across the barrier. Memory-clobbered asm
        // before/after the barrier pins LDS ops on their side of it. ----
        if (jt < 15) {
            if (jt <= 12)      asm volatile("s_waitcnt vmcnt(4)" ::: "memory");
            else if (jt == 13) asm volatile("s_waitcnt vmcnt(2)" ::: "memory");
            else               asm volatile("s_waitcnt vmcnt(0)" ::: "memory");
            __builtin_amdgcn_s_barrier();
            asm volatile("" ::: "memory");
        }
    }

    // ---- flush mins to global with norms pre-added (device-scope atomics) ----
    __syncthreads();   // orders col_min_sm atomics before the re-read below
    #pragma unroll
    for (int e = tid; e < 512; e += 256) {
        float v = fdec(col_min_sm[e]) + y2_sm[e];       // + y2_j for col e
        atomicMin(&g_colmin[n * T + j0 + e], fenc(v));
    }
    #pragma unroll
    for (int mi = 0; mi < 2; ++mi)
        #pragma unroll
        for (int r = 0; r < 4; ++r) {
            float v = rmin[mi * 4 + r] + x2v[mi * 4 + r];   // + x2_i for this row
            v = fminf(v, __shfl_xor(v, 1));
            v = fminf(v, __shfl_xor(v, 2));
            v = fminf(v, __shfl_xor(v, 4));
            v = fminf(v, __shfl_xor(v, 8));
            if (l16 == 0)
                atomicMin(&g_rowmin[n * T + i0 + wave * 32 + mi * 16 + quad * 4 + r], fenc(v));
        }

    // ---- fence-free completion protocol ----
    __builtin_amdgcn_s_waitcnt(0);   // this wave's atomics acked at coherent point
    __syncthreads();                 // all waves of block done
    if (tid == 0)
        last_sm = __hip_atomic_fetch_add(&batch_cnt[n], 1u, __ATOMIC_RELAXED,
                                         __HIP_MEMORY_SCOPE_AGENT);
    __syncthreads();
    if (last_sm != 15u) return;

    // last block of batch n: reduce its 1024 row/col mins (already full d^2)
    float sc = 0.f, sr = 0.f;
    for (int e = tid; e < T; e += 256) {
        unsigned cu = __hip_atomic_load(&g_colmin[n * T + e], __ATOMIC_RELAXED,
                                        __HIP_MEMORY_SCOPE_AGENT);
        unsigned ru = __hip_atomic_load(&g_rowmin[n * T + e], __ATOMIC_RELAXED,
                                        __HIP_MEMORY_SCOPE_AGENT);
        sc += sqrtf(fmaxf(fdec(cu), 0.f));
        sr += sqrtf(fmaxf(fdec(ru), 0.f));
    }
    #pragma unroll
    for (int o = 1; o < 64; o <<= 1) {
        sc += __shfl_xor(sc, o);
        sr += __shfl_xor(sr, o);
    }
    if (lane == 0) { red_sm[wave] = sc; red_sm[4 + wave] = sr; }
    __syncthreads();
    if (tid == 0) {
        atomicAdd(&sums[0], red_sm[0] + red_sm[1] + red_sm[2] + red_sm[3]);
        atomicAdd(&sums[1], red_sm[4] + red_sm[5] + red_sm[6] + red_sm[7]);
        __builtin_amdgcn_s_waitcnt(0);   // sums adds acked before counter bump
        unsigned old = __hip_atomic_fetch_add(g_cnt, 1u, __ATOMIC_RELAXED,
                                              __HIP_MEMORY_SCOPE_AGENT);
        if (old == NB - 1) {
            float a = __hip_atomic_load(&sums[0], __ATOMIC_RELAXED, __HIP_MEMORY_SCOPE_AGENT);
            float b = __hip_atomic_load(&sums[1], __ATOMIC_RELAXED, __HIP_MEMORY_SCOPE_AGENT);
            out[0] = fmaxf(a, b) * (1.0f / 67108864.0f);
        }
    }
}

extern "C" void kernel_launch(void* const* d_in, const int* in_sizes, int n_in,
                              void* d_out, int out_size, void* d_ws, size_t ws_size,
                              hipStream_t stream) {
    const float* x = (const float*)d_in[0];
    const float* y = (const float*)d_in[1];
    float* out = (float*)d_out;

    char* ws = (char*)d_ws;
    unsigned* g_colmin  = (unsigned*)(ws);                     // 256 KB
    unsigned* g_rowmin  = (unsigned*)(ws + 256 * 1024);        // 256 KB
    float*    y2g       = (float*)(ws + 512 * 1024);           // 256 KB
    float*    sums      = (float*)(ws + 768 * 1024);           // 2 f32
    unsigned* batch_cnt = (unsigned*)(ws + 768 * 1024 + 256);  // 64 u32
    unsigned* g_cnt     = (unsigned*)(ws + 768 * 1024 + 2048); // 1 u32
    short*    ybf       = (short*)(ws + 1024 * 1024);          // 16 MB

    wmd_prep<<<(NB * T * HD / 4) / 256, 256, 0, stream>>>(
        y, ybf, y2g, g_colmin, g_rowmin, sums, batch_cnt, g_cnt);
    wmd_main<<<dim3(16, NB), 256, 0, stream>>>(
        x, ybf, y2g, g_colmin, g_rowmin, sums, batch_cnt, g_cnt, out);
}